// Round 3
// baseline (217.865 us; speedup 1.0000x reference)
//
#include <hip/hip_runtime.h>
#include <hip/hip_bf16.h>

#define B_ 4
#define S_ 2048
#define D_ 1024
#define MTOT (B_ * S_)

typedef __attribute__((ext_vector_type(8))) short bf16x8;
typedef __attribute__((ext_vector_type(4))) float f32x4;

__device__ __forceinline__ unsigned short f2bf(float f) {
  union { float f; unsigned int u; } v; v.f = f;
  unsigned int r = v.u + 0x7FFFu + ((v.u >> 16) & 1u);
  return (unsigned short)(r >> 16);
}
__device__ __forceinline__ float bf2f(unsigned short u) {
  union { unsigned int u; float f; } v; v.u = ((unsigned int)u) << 16;
  return v.f;
}

// ---------------- fp32 -> bf16 convert (vectorized) ----------------
__global__ void cvt_f32_bf16(const float* __restrict__ in, unsigned short* __restrict__ outp, int n4) {
  int i = blockIdx.x * blockDim.x + threadIdx.x;
  if (i >= n4) return;
  float4 v = ((const float4*)in)[i];
  ushort4 o;
  o.x = f2bf(v.x); o.y = f2bf(v.y); o.z = f2bf(v.z); o.w = f2bf(v.w);
  ((ushort4*)outp)[i] = o;
}

// -------- row L2-normalize bf16 -> bf16; QKb is [8192][2048], half 0=Q, 1=K --------
__global__ __launch_bounds__(256) void rownorm_bf16(const unsigned short* __restrict__ QKb,
                                                    unsigned short* __restrict__ Qn,
                                                    unsigned short* __restrict__ Kn) {
  int row = blockIdx.x;
  int half = blockIdx.y;
  int tid = threadIdx.x;
  ushort4 u = *(const ushort4*)(QKb + (long)row * 2048 + half * 1024 + tid * 4);
  float x0 = bf2f(u.x), x1 = bf2f(u.y), x2 = bf2f(u.z), x3 = bf2f(u.w);
  float ss = x0 * x0 + x1 * x1 + x2 * x2 + x3 * x3;
#pragma unroll
  for (int o = 1; o < 64; o <<= 1) ss += __shfl_xor(ss, o);
  __shared__ float wsum[4];
  if ((tid & 63) == 0) wsum[tid >> 6] = ss;
  __syncthreads();
  float rn = rsqrtf(wsum[0] + wsum[1] + wsum[2] + wsum[3]);
  ushort4 o;
  o.x = f2bf(x0 * rn); o.y = f2bf(x1 * rn); o.z = f2bf(x2 * rn); o.w = f2bf(x3 * rn);
  unsigned short* op = half ? Kn : Qn;
  *(ushort4*)(op + (long)row * D_ + tid * 4) = o;
}

// ================= 256x256 8-phase MFMA GEMM: C = A[M,K] @ B[N,K]^T =================
// 512 threads (8 waves, 2M x 4N), BK=64, 128KiB dynamic LDS, double-buffered.
// T2: XOR-swizzle (col ^= (row&7)<<4), applied to global SOURCE (staging) and LDS READ.
// T3/T4: 4 phases per K-tile, counted vmcnt(8) (stage issued 2 K-tiles ahead at ph3).
// T5: setprio around each 16-MFMA cluster.
// EPI: 0 fp32 out; 1 bf16 out; 2 bf16*mask; 3 bf16 scatter to per-batch [D][S]

#define GLDS16(g, l)                                                                   \
  __builtin_amdgcn_global_load_lds((const __attribute__((address_space(1))) void*)(g), \
                                   (__attribute__((address_space(3))) void*)(l), 16, 0, 0)

template <int EPI, int KK>
__global__ __launch_bounds__(512, 2) void gemm8(const unsigned short* __restrict__ A,
                                                const unsigned short* __restrict__ B,
                                                void* __restrict__ Cv, int N,
                                                long strideA, long strideB, long strideC,
                                                const int* __restrict__ masks) {
  constexpr int NT = KK / 64;
  extern __shared__ __align__(16) char smem[];
  char* smA = smem;           // [2][32768] : 256 rows x 128B, swizzled
  char* smB = smem + 65536;   // [2][32768]

  const int z = blockIdx.z;
  const unsigned short* Ab = A + (long)z * strideA;
  const unsigned short* Bb = B + (long)z * strideB;
  const int t = threadIdx.x;
  const int lane = t & 63, w = t >> 6;
  const int wm = w >> 2, wn = w & 3;          // wave -> (row-half, col-quarter)
  const int fr = lane & 15, fq = lane >> 4;
  const int brow = blockIdx.x * 256, bcol = blockIdx.y * 256;

  // ---- staging addresses: thread t covers LDS bytes [t*16 + j*8192) j=0..3 ----
  // LDS row = (t>>3) + j*64, colbyte = (t&7)*16; source col pre-XOR'd (rule 21)
  const int srow = t >> 3;
  const int sswz = ((t & 7) * 16) ^ ((srow & 7) << 4);
  const char* gA = (const char*)(Ab + (long)(brow + srow) * KK) + sswz;
  const char* gB = (const char*)(Bb + (long)(bcol + srow) * KK) + sswz;
  const long jstr = (long)64 * KK * 2;

#define STAGE8(kt2, bf)                                   \
  do {                                                    \
    const char* ga_ = gA + (long)(kt2) * 128;             \
    const char* gb_ = gB + (long)(kt2) * 128;             \
    char* la_ = smA + (bf) * 32768 + t * 16;              \
    char* lb_ = smB + (bf) * 32768 + t * 16;              \
    GLDS16(ga_, la_);                                     \
    GLDS16(ga_ + jstr, la_ + 8192);                       \
    GLDS16(ga_ + 2 * jstr, la_ + 16384);                  \
    GLDS16(ga_ + 3 * jstr, la_ + 24576);                  \
    GLDS16(gb_, lb_);                                     \
    GLDS16(gb_ + jstr, lb_ + 8192);                       \
    GLDS16(gb_ + 2 * jstr, lb_ + 16384);                  \
    GLDS16(gb_ + 3 * jstr, lb_ + 24576);                  \
  } while (0)

  // ---- ds_read addressing: frag row&7 == fr&7, so swizzle is lane-constant ----
  const int c0 = (fq * 16) ^ ((fr & 7) << 4);
  const int c1 = c0 ^ 64;  // k-step 1 (bytes 64..127 of row)
  const int arow = (wm * 128 + fr) * 128;
  const int brw = (wn * 64 + fr) * 128;

  f32x4 acc[8][4];
#pragma unroll
  for (int m = 0; m < 8; m++)
#pragma unroll
    for (int n = 0; n < 4; n++) acc[m][n] = (f32x4){0.f, 0.f, 0.f, 0.f};
  bf16x8 af[4][2], bv[2][2][2];

#define LDA(qm)                                                               \
  do {                                                                        \
    _Pragma("unroll") for (int mf = 0; mf < 4; ++mf) {                        \
      af[mf][0] = *(const bf16x8*)(pa + c0 + (((qm)*64 + mf * 16) << 7));     \
      af[mf][1] = *(const bf16x8*)(pa + c1 + (((qm)*64 + mf * 16) << 7));     \
    }                                                                         \
  } while (0)

#define LDB(qn)                                                               \
  do {                                                                        \
    _Pragma("unroll") for (int nf = 0; nf < 2; ++nf) {                        \
      bv[(qn)][nf][0] = *(const bf16x8*)(pb + c0 + (((qn)*32 + nf * 16) << 7)); \
      bv[(qn)][nf][1] = *(const bf16x8*)(pb + c1 + (((qn)*32 + nf * 16) << 7)); \
    }                                                                         \
  } while (0)

#define MFMAQ(qm, qn)                                                         \
  do {                                                                        \
    _Pragma("unroll") for (int ks = 0; ks < 2; ++ks)                          \
    _Pragma("unroll") for (int nf = 0; nf < 2; ++nf)                          \
    _Pragma("unroll") for (int mf = 0; mf < 4; ++mf)                          \
      acc[(qm)*4 + mf][(qn)*2 + nf] = __builtin_amdgcn_mfma_f32_16x16x32_bf16(\
          af[mf][ks], bv[(qn)][nf][ks], acc[(qm)*4 + mf][(qn)*2 + nf], 0, 0, 0); \
  } while (0)

#define BARW()                                                \
  do {                                                        \
    __builtin_amdgcn_s_barrier();                             \
    asm volatile("s_waitcnt lgkmcnt(0)" ::: "memory");        \
    __builtin_amdgcn_sched_barrier(0);                        \
  } while (0)

  // prologue: tiles 0,1 in flight; wait tile 0 (8 of 16 loads) -> counted
  STAGE8(0, 0);
  STAGE8(1, 1);
  asm volatile("s_waitcnt vmcnt(8)" ::: "memory");
  __builtin_amdgcn_s_barrier();

#pragma unroll 2
  for (int kt = 0; kt < NT; ++kt) {
    const int cur = kt & 1;
    const char* pa = smA + cur * 32768 + arow;
    const char* pb = smB + cur * 32768 + brw;
    // ph0: quadrant (0,0)
    LDA(0);
    LDB(0);
    BARW();
    __builtin_amdgcn_s_setprio(1);
    MFMAQ(0, 0);
    __builtin_amdgcn_s_setprio(0);
    __builtin_amdgcn_s_barrier();
    // ph1: quadrant (0,1)
    LDB(1);
    BARW();
    __builtin_amdgcn_s_setprio(1);
    MFMAQ(0, 1);
    __builtin_amdgcn_s_setprio(0);
    __builtin_amdgcn_s_barrier();
    // ph2: quadrant (1,1)
    LDA(1);
    BARW();
    __builtin_amdgcn_s_setprio(1);
    MFMAQ(1, 1);
    __builtin_amdgcn_s_setprio(0);
    __builtin_amdgcn_s_barrier();
    // ph3: quadrant (1,0); buf `cur` is dead for reads -> stage tile kt+2 into it
    if (kt + 2 < NT) STAGE8(kt + 2, cur);
    BARW();
    __builtin_amdgcn_s_setprio(1);
    MFMAQ(1, 0);
    __builtin_amdgcn_s_setprio(0);
    // K-tile boundary: wait tile kt+1 landed (counted), then barrier
    if (kt + 1 < NT) {
      if (kt + 2 < NT)
        asm volatile("s_waitcnt vmcnt(8)" ::: "memory");
      else
        asm volatile("s_waitcnt vmcnt(0)" ::: "memory");
      __builtin_amdgcn_s_barrier();
    }
  }
#undef STAGE8
#undef LDA
#undef LDB
#undef MFMAQ
#undef BARW

  long cbase = (long)z * strideC;
#pragma unroll
  for (int Mi = 0; Mi < 8; ++Mi) {
#pragma unroll
    for (int Ni = 0; Ni < 4; ++Ni) {
#pragma unroll
      for (int r = 0; r < 4; ++r) {
        int grow = brow + wm * 128 + Mi * 16 + fq * 4 + r;
        int gcol = bcol + wn * 64 + Ni * 16 + fr;
        float v = acc[Mi][Ni][r];
        if constexpr (EPI == 0) {
          ((float*)Cv)[cbase + (long)grow * N + gcol] = v;
        } else if constexpr (EPI == 1) {
          ((unsigned short*)Cv)[cbase + (long)grow * N + gcol] = f2bf(v);
        } else if constexpr (EPI == 2) {
          // keep score where (k > q) OR key is padding (masks==0); else zero
          bool keep = (gcol > grow) || (masks[z * S_ + gcol] == 0);
          ((unsigned short*)Cv)[cbase + (long)grow * N + gcol] = keep ? f2bf(v) : (unsigned short)0;
        } else {
          // Vt direct: A=Wv (grow=d), B=X (gcol=b*S+s) -> Vt[b][d][s]
          int b = gcol >> 11, s = gcol & (S_ - 1);
          ((unsigned short*)Cv)[(long)b * D_ * S_ + (long)grow * S_ + s] = f2bf(v);
        }
      }
    }
  }
}

extern "C" void kernel_launch(void* const* d_in, const int* in_sizes, int n_in, void* d_out,
                              int out_size, void* d_ws, size_t ws_size, hipStream_t stream) {
  (void)in_sizes; (void)n_in; (void)out_size; (void)ws_size;
  const float* X = (const float*)d_in[0];
  const int* masks = (const int*)d_in[1];
  const float* Wq = (const float*)d_in[2];
  const float* Wk = (const float*)d_in[3];
  const float* Wv = (const float*)d_in[4];
  float* out = (float*)d_out;

  char* ws = (char*)d_ws;
  unsigned short* Xb = (unsigned short*)ws;   ws += (long)MTOT * D_ * 2;
  unsigned short* Wqkb = (unsigned short*)ws; ws += (long)2 * D_ * D_ * 2;
  unsigned short* Wvb = (unsigned short*)ws;  ws += (long)D_ * D_ * 2;
  unsigned short* QKb = (unsigned short*)ws;  ws += (long)MTOT * 2 * D_ * 2;
  unsigned short* Qn = (unsigned short*)ws;   ws += (long)MTOT * D_ * 2;
  unsigned short* Kn = (unsigned short*)ws;   ws += (long)MTOT * D_ * 2;
  unsigned short* Vt = (unsigned short*)ws;   ws += (long)MTOT * D_ * 2;
  unsigned short* Sm = (unsigned short*)ws;   ws += (long)B_ * S_ * S_ * 2;

  constexpr unsigned SMEM = 131072;
  // allow >64KB dynamic LDS (no-op / harmless if unnecessary on ROCm)
  (void)hipFuncSetAttribute((const void*)gemm8<1, 1024>, hipFuncAttributeMaxDynamicSharedMemorySize, SMEM);
  (void)hipFuncSetAttribute((const void*)gemm8<3, 1024>, hipFuncAttributeMaxDynamicSharedMemorySize, SMEM);
  (void)hipFuncSetAttribute((const void*)gemm8<2, 1024>, hipFuncAttributeMaxDynamicSharedMemorySize, SMEM);
  (void)hipFuncSetAttribute((const void*)gemm8<0, 2048>, hipFuncAttributeMaxDynamicSharedMemorySize, SMEM);

  // fp32 -> bf16 converts (Wq,Wk into contiguous Wqkb)
  int n4x = MTOT * D_ / 4;
  cvt_f32_bf16<<<(n4x + 255) / 256, 256, 0, stream>>>(X, Xb, n4x);
  int n4w = D_ * D_ / 4;
  cvt_f32_bf16<<<(n4w + 255) / 256, 256, 0, stream>>>(Wq, Wqkb, n4w);
  cvt_f32_bf16<<<(n4w + 255) / 256, 256, 0, stream>>>(Wk, Wqkb + (long)D_ * D_, n4w);
  cvt_f32_bf16<<<(n4w + 255) / 256, 256, 0, stream>>>(Wv, Wvb, n4w);

  // [Q|K] = X @ [Wq|Wk]^T  (bf16 out, M=8192, N=2048, K=1024)
  gemm8<1, 1024><<<dim3(MTOT / 256, 2 * D_ / 256, 1), 512, SMEM, stream>>>(
      Xb, Wqkb, QKb, 2 * D_, 0, 0, 0, nullptr);
  // normalize rows of Q-half and K-half
  rownorm_bf16<<<dim3(MTOT, 2), 256, 0, stream>>>(QKb, Qn, Kn);
  // Vt[b][d][s] = sum_k Wv[d][k] X[b*S+s][k]  (M=1024, N=8192, K=1024, scatter)
  gemm8<3, 1024><<<dim3(D_ / 256, MTOT / 256, 1), 512, SMEM, stream>>>(
      Wvb, Xb, Vt, MTOT, 0, 0, 0, nullptr);
  // S[b] = (Qn[b] @ Kn[b]^T) * mask  (bf16, M=N=2048, K=1024)
  gemm8<2, 1024><<<dim3(S_ / 256, S_ / 256, B_), 512, SMEM, stream>>>(
      Qn, Kn, Sm, S_, (long)S_ * D_, (long)S_ * D_, (long)S_ * S_, masks);
  // out[b] = S[b] @ V[b]  (A = Sm [S][S], B = Vt [D][S], fp32 out, K=2048)
  gemm8<0, 2048><<<dim3(S_ / 256, D_ / 256, B_), 512, SMEM, stream>>>(
      Sm, Vt, out, D_, (long)S_ * S_, (long)D_ * S_, (long)S_ * D_, nullptr);
}